// Round 19
// baseline (396.563 us; speedup 1.0000x reference)
//
#include <hip/hip_runtime.h>
#include <hip/hip_bf16.h>

// LSTM block, fused. Inputs fp32, outputs fp32. bf16 MFMA internally.
// GATE-SPLIT 16-wave version: 1024-thread blocks (16 waves/CU -- 2x the
// occupancy of the weights-in-regs 8-wave design). Each wave owns ONE gate x
// 32 cols for GEMM1 (Breg = 64 VGPR). Activated gates (sigmoid/tanh as
// m*sig(k*a)+c, wave-uniform k/m/c) exchanged via LDS gex[row][col][4g] bf16;
// elementwise reads one b64 per (row,col). GEMM2: wave = one 16x16 tile,
// Wch frags re-read from L2 per tile. A-path: r18's land-DMA + cvt-pass.
// Barriers: A (lgkmcnt0, gex) + B (lgkmcnt0 vmcnt4, cex + DMA publish).
// LDS 136K: abuf 2x16K | land 2x32K | gex 32K | cex 8K.

typedef __attribute__((ext_vector_type(8))) short bf16x8;   // 8 bf16 = 4 VGPRs
typedef __attribute__((ext_vector_type(4))) float f32x4;

#define AB0   0
#define AB1   16384
#define LAND0 32768
#define LAND1 65536
#define GEX   98304
#define CEX   131072

static __device__ __forceinline__ unsigned short f2bf(float f) {
    unsigned int u = __builtin_bit_cast(unsigned int, f);
    u += 0x7FFFu + ((u >> 16) & 1u);      // RNE
    return (unsigned short)(u >> 16);
}

static __device__ __forceinline__ unsigned int cvtpk(float lo, float hi) {
    unsigned int r;
    asm("v_cvt_pk_bf16_f32 %0, %1, %2" : "=v"(r) : "v"(lo), "v"(hi));
    return r;
}

static __device__ __forceinline__ bf16x8 cvt8(f32x4 a, f32x4 b) {
    union { bf16x8 v; unsigned int w[4]; } r;
    r.w[0] = cvtpk(a[0], a[1]);
    r.w[1] = cvtpk(a[2], a[3]);
    r.w[2] = cvtpk(b[0], b[1]);
    r.w[3] = cvtpk(b[2], b[3]);
    return r.v;
}

static __device__ __forceinline__ float bf2f_lo(unsigned int u) {
    return __builtin_bit_cast(float, u << 16);
}
static __device__ __forceinline__ float bf2f_hi(unsigned int u) {
    return __builtin_bit_cast(float, u & 0xFFFF0000u);
}

static __device__ __forceinline__ float fsig(float x) {
    float e = __builtin_amdgcn_exp2f(-1.44269504f * x);
    return __builtin_amdgcn_rcpf(1.0f + e);
}
static __device__ __forceinline__ float ftanh(float x) {
    float e = __builtin_amdgcn_exp2f(2.8853900818f * x);
    return 1.0f - 2.0f * __builtin_amdgcn_rcpf(e + 1.0f);
}

static __device__ __forceinline__ void gload16(const void* gsrc, void* ldst) {
    __builtin_amdgcn_global_load_lds(
        (const __attribute__((address_space(1))) unsigned int*)gsrc,
        (__attribute__((address_space(3))) unsigned int*)ldst,
        16, 0, 0);
}

#define MEMFENCE asm volatile("" ::: "memory")

// ---------------- weight prep ----------------
// WgF2: 256 frags of 1KB; idx = wvp*16 + cf*8 + ks  (wvp: g1=wvp&3, cg=wvp>>2)
//   lane l: col = cg*32 + cf*16 + (l&15) of gate g1; k = ks*32 + (l>>4)*8 ..+8
// WchF: idx = kt*8 + c8: col = c8*16 + (l&15); k = kt*32 + (l>>4)*8
__global__ void prep_weights(const float* __restrict__ Wf, const float* __restrict__ Wi,
                             const float* __restrict__ Wc, const float* __restrict__ Wo,
                             const float* __restrict__ Wch,
                             unsigned short* __restrict__ WgF2,  // 512*256
                             unsigned short* __restrict__ WchF)  // 128*128
{
    int u = blockIdx.x * 256 + threadIdx.x;
    if (u < 16384) {
        int lane = u & 63, rest = u >> 6;
        int ks = rest & 7, cf = (rest >> 3) & 1, wvp = rest >> 4;
        int g1 = wvp & 3, cg = wvp >> 2;
        int l15 = lane & 15, lg = lane >> 4;
        int colg = cg * 32 + cf * 16 + l15;
        int k0 = ks * 32 + lg * 8;
        const float* W = (g1 == 0) ? Wf : (g1 == 1) ? Wi : (g1 == 2) ? Wc : Wo;
        union { bf16x8 v; unsigned short s[8]; } r;
#pragma unroll
        for (int i = 0; i < 8; ++i) r.s[i] = f2bf(W[(size_t)(k0 + i) * 128 + colg]);
        *(bf16x8*)(WgF2 + (size_t)u * 8) = r.v;
    } else if (u < 16384 + 2048) {
        int u2 = u - 16384;
        int lane = u2 & 63, c8 = (u2 >> 6) & 7, kt = u2 >> 9;
        int l15 = lane & 15, lg = lane >> 4;
        int col = c8 * 16 + l15, k0 = kt * 32 + lg * 8;
        union { bf16x8 v; unsigned short s[8]; } r;
#pragma unroll
        for (int i = 0; i < 8; ++i) r.s[i] = f2bf(Wch[(size_t)(k0 + i) * 128 + col]);
        *(bf16x8*)(WchF + (size_t)u2 * 8) = r.v;
    }
}

// One 32-row tile. T runtime; P (parity) compile-time. CIN/COUT c ping-pong.
#define TILE_BODY(T, P, CIN, COUT)                                              \
  do {                                                                          \
    const long m0 = base + (long)(T) * 32;                                      \
    /* 1. cvt(t+1): land[P^1] -> abuf[P^1] (published by prev barrier-B) */     \
    if ((T) < 31) {                                                             \
      const char* lnb = lds + ((P) ? LAND0 : LAND1) + rowC * 1024;              \
      f32x4 q0 = *(const f32x4*)(lnb + (((u0C    ) ^ swzC) << 4));              \
      f32x4 q1 = *(const f32x4*)(lnb + (((u0C + 1) ^ swzC) << 4));              \
      *(bf16x8*)(lds + ((P) ? AB0 : AB1) + aoffC) = cvt8(q0, q1);               \
    }                                                                           \
    MEMFENCE;                                                                   \
    /* 2. c-loads(t+1) -> COUT (4 loads) */                                     \
    if ((T) < 31) {                                                             \
      _Pragma("unroll")                                                         \
      for (int r = 0; r < 4; ++r)                                               \
        COUT[r] = cg[(m0 + 32 + rh * 16 + lg * 4 + r) * 128 + colc2];           \
    }                                                                           \
    MEMFENCE;                                                                   \
    /* 3. A-DMA(t+2) -> land[P] (2 ops) */                                      \
    if ((T) < 30) {                                                             \
      _Pragma("unroll")                                                         \
      for (int j = 0; j < 2; ++j)                                               \
        gload16(dmaA + (m0 + 64 + j * 16 + wv) * 128,                           \
                lds + ((P) ? LAND1 : LAND0) + (j * 16 + wv) * 1024 + lane * 16);\
    }                                                                           \
    MEMFENCE;                                                                   \
    /* 4. GEMM1(t): abuf[P] x Breg (16 b128 reads, 32 MFMA) */                  \
    f32x4 a00 = {0.f,0.f,0.f,0.f}, a01 = {0.f,0.f,0.f,0.f};                     \
    f32x4 a10 = {0.f,0.f,0.f,0.f}, a11 = {0.f,0.f,0.f,0.f};                     \
    {                                                                           \
      const char* ab = lds + ((P) ? AB1 : AB0);                                 \
      _Pragma("unroll")                                                         \
      for (int ks = 0; ks < 8; ++ks) {                                          \
        bf16x8 af0 = *(const bf16x8*)(ab + ks * 1024 + ((lane * 16) ^ (ks << 4)));       \
        bf16x8 af1 = *(const bf16x8*)(ab + (8 + ks) * 1024 + ((lane * 16) ^ (ks << 4))); \
        a00 = __builtin_amdgcn_mfma_f32_16x16x32_bf16(af0, Breg[ks][0], a00, 0, 0, 0);   \
        a01 = __builtin_amdgcn_mfma_f32_16x16x32_bf16(af0, Breg[ks][1], a01, 0, 0, 0);   \
        a10 = __builtin_amdgcn_mfma_f32_16x16x32_bf16(af1, Breg[ks][0], a10, 0, 0, 0);   \
        a11 = __builtin_amdgcn_mfma_f32_16x16x32_bf16(af1, Breg[ks][1], a11, 0, 0, 0);   \
      }                                                                         \
    }                                                                           \
    /* 5. gex write: activated gates (m*sig(k*a)+c), bf16 */                    \
    _Pragma("unroll")                                                           \
    for (int r4 = 0; r4 < 4; ++r4) {                                            \
      int rA = lg * 4 + r4, rB = 16 + lg * 4 + r4;                              \
      *(unsigned short*)(lds + GEX + rA * 1024 + gxc0) =                        \
          f2bf(actM * fsig(actK * (a00[r4] + bb0)) + actC);                     \
      *(unsigned short*)(lds + GEX + rA * 1024 + gxc1) =                        \
          f2bf(actM * fsig(actK * (a01[r4] + bb1)) + actC);                     \
      *(unsigned short*)(lds + GEX + rB * 1024 + gxc0) =                        \
          f2bf(actM * fsig(actK * (a10[r4] + bb0)) + actC);                     \
      *(unsigned short*)(lds + GEX + rB * 1024 + gxc1) =                        \
          f2bf(actM * fsig(actK * (a11[r4] + bb1)) + actC);                     \
    }                                                                           \
    /* 6. BARRIER-A: publish gex (+ abuf from cvt) */                           \
    asm volatile("s_waitcnt lgkmcnt(0)" ::: "memory");                          \
    __builtin_amdgcn_sched_barrier(0);                                          \
    __builtin_amdgcn_s_barrier();                                               \
    __builtin_amdgcn_sched_barrier(0);                                          \
    /* 7. elementwise: gex b64 -> c_new; store c; cex frag write; keep o */     \
    float ok0, ok1, ok2, ok3;                                                   \
    {                                                                           \
      _Pragma("unroll")                                                         \
      for (int r4 = 0; r4 < 4; ++r4) {                                          \
        int row = rh * 16 + lg * 4 + r4;                                        \
        uint2 gv = *(const uint2*)(lds + GEX + row * 1024 + colc2 * 8);         \
        float f_ = bf2f_lo(gv.x), i_ = bf2f_hi(gv.x);                           \
        float ct_ = bf2f_lo(gv.y), o_ = bf2f_hi(gv.y);                          \
        float cv_ = f_ * CIN[r4] + i_ * ct_;                                    \
        coutp[(m0 + row) * 128 + colc2] = cv_;                                  \
        *(unsigned short*)(lds + cexWB + (lg * 4 + r4) * 16) = f2bf(cv_);       \
        if (r4 == 0) ok0 = o_; else if (r4 == 1) ok1 = o_;                      \
        else if (r4 == 2) ok2 = o_; else ok3 = o_;                              \
      }                                                                         \
    }                                                                           \
    /* 8. BARRIER-B: publish cex; vmcnt(4) retires A-DMA for all waves */       \
    asm volatile("s_waitcnt lgkmcnt(0) vmcnt(4)" ::: "memory");                 \
    __builtin_amdgcn_sched_barrier(0);                                          \
    __builtin_amdgcn_s_barrier();                                               \
    __builtin_amdgcn_sched_barrier(0);                                          \
    /* 9. GEMM2(t): cex frags x Wch (L2) ; 10. h-epilogue */                    \
    {                                                                           \
      f32x4 acc2 = {0.f, 0.f, 0.f, 0.f};                                        \
      _Pragma("unroll")                                                         \
      for (int kt = 0; kt < 4; ++kt) {                                          \
        bf16x8 w = *(const bf16x8*)(WchF + (size_t)((kt * 8 + cg2) * 512 + lane * 8)); \
        bf16x8 p = *(const bf16x8*)(lds + CEX + (rh * 4 + kt) * 1024 + lane * 16);     \
        acc2 = __builtin_amdgcn_mfma_f32_16x16x32_bf16(p, w, acc2, 0, 0, 0);    \
      }                                                                         \
      houtp[(m0 + rh * 16 + lg * 4 + 0) * 128 + colc2] = ok0 * ftanh(acc2[0] + bchb); \
      houtp[(m0 + rh * 16 + lg * 4 + 1) * 128 + colc2] = ok1 * ftanh(acc2[1] + bchb); \
      houtp[(m0 + rh * 16 + lg * 4 + 2) * 128 + colc2] = ok2 * ftanh(acc2[2] + bchb); \
      houtp[(m0 + rh * 16 + lg * 4 + 3) * 128 + colc2] = ok3 * ftanh(acc2[3] + bchb); \
    }                                                                           \
  } while (0)

// ---------------- fused kernel: 1024 rows per 1024-thread block ----------------
__global__ __launch_bounds__(1024, 4) void lstm_fused(
    const float* __restrict__ xg, const float* __restrict__ hg, const float* __restrict__ cg,
    const float* __restrict__ bfv, const float* __restrict__ biv,
    const float* __restrict__ bcv, const float* __restrict__ bov,
    const float* __restrict__ bchv,
    const unsigned short* __restrict__ WgF2, const unsigned short* __restrict__ WchF,
    float* __restrict__ out, int nrows)
{
    __shared__ uint4 lds4[8704];                 // 136 KB
    char* lds = (char*)lds4;

    const int tid  = threadIdx.x;
    const int lane = tid & 63;
    const int wv   = tid >> 6;                   // 0..15
    const int l15  = lane & 15;
    const int lg   = lane >> 4;
    const int g1   = wv & 3;                     // GEMM1 gate
    const int cgp  = wv >> 2;                    // GEMM1 col-group (32 cols)
    const int rh   = wv >> 3;                    // GEMM2 row-half
    const int cg2  = wv & 7;                     // GEMM2 col-group (16 cols)
    const long base = (long)blockIdx.x << 10;    // 1024 rows per block

    float* houtp = out;
    float* coutp = out + (size_t)nrows * 128;

    const int colc2 = cg2 * 16 + l15;            // elementwise/GEMM2 column
    const float bchb = bchv[colc2];

    // GEMM1 biases + wave-uniform activation constants (tanh = 2*sig(2x)-1)
    const float* bsrc = (g1 == 0) ? bfv : (g1 == 1) ? biv : (g1 == 2) ? bcv : bov;
    const float bb0 = bsrc[cgp * 32 + l15];
    const float bb1 = bsrc[cgp * 32 + 16 + l15];
    const float actK = (g1 == 2) ? 2.f : 1.f;
    const float actM = (g1 == 2) ? 2.f : 1.f;
    const float actC = (g1 == 2) ? -1.f : 0.f;

    // gex write byte-offsets (col part) for cf=0,1
    const int gxc0 = (cgp * 32 + l15) * 8 + g1 * 2;
    const int gxc1 = (cgp * 32 + 16 + l15) * 8 + g1 * 2;
    // cex write base (frag-linear): kt=cg2>>1, lgf=(cg2&1)*2+(l15>>3), e=l15&7
    const int cexWB = CEX + (rh * 4 + (cg2 >> 1)) * 1024
                    + ((cg2 & 1) * 2 + (l15 >> 3)) * 256 + (l15 & 7) * 2;

    // ---- GEMM1 weights: 64 VGPR/wave (one gate x 32 cols, K=256)
    bf16x8 Breg[8][2];
#pragma unroll
    for (int ks = 0; ks < 8; ++ks) {
        Breg[ks][0] = *(const bf16x8*)(WgF2 + (size_t)((wv * 16 + 0 * 8 + ks) * 512 + lane * 8));
        Breg[ks][1] = *(const bf16x8*)(WgF2 + (size_t)((wv * 16 + 1 * 8 + ks) * 512 + lane * 8));
    }

    // ---- A-DMA source: lane stages 16B unit gu = lane ^ (wv&7) of its rows
    //      land[row][u] = G[row][u ^ (row&7)]; wave wv stages rows {wv, 16+wv}
    const int gu = lane ^ (wv & 7);
    const float* dmaA = ((gu < 32) ? (xg + gu * 4) : (hg + (gu - 32) * 4));

    // ---- cvt-pass coords: thread converts 8 k-elems of one row (1 frag slot)
    const int laneC = tid & 63;
    const int ksC   = (tid >> 6) & 7;
    const int rfC   = tid >> 9;
    const int rowC  = rfC * 16 + (laneC & 15);   // local row 0..31
    const int swzC  = rowC & 7;
    const int u0C   = ksC * 8 + (laneC >> 4) * 2;
    const int aoffC = (rfC * 8 + ksC) * 1024 + ((laneC * 16) ^ (ksC << 4));
    const int k0C   = ksC * 32 + (laneC >> 4) * 8;
    const float* asrcC = (k0C < 128) ? (xg + k0C) : (hg + (k0C - 128));

    // ---- prologue: c(0) -> c0; A(1) DMA -> land1; A(0) direct -> abuf0
    float c0[4], c1[4];
#pragma unroll
    for (int r = 0; r < 4; ++r)
        c0[r] = cg[(base + rh * 16 + lg * 4 + r) * 128 + colc2];
    MEMFENCE;
#pragma unroll
    for (int j = 0; j < 2; ++j)
        gload16(dmaA + (base + 32 + j * 16 + wv) * 128,
                lds + LAND1 + (j * 16 + wv) * 1024 + lane * 16);
    MEMFENCE;
    {
        const float* s = asrcC + (base + rowC) * 128;
        f32x4 q0 = ((const f32x4*)s)[0];
        f32x4 q1 = ((const f32x4*)s)[1];
        *(bf16x8*)(lds + AB0 + aoffC) = cvt8(q0, q1);
    }
    asm volatile("s_waitcnt lgkmcnt(0) vmcnt(0)" ::: "memory");
    __builtin_amdgcn_sched_barrier(0);
    __builtin_amdgcn_s_barrier();
    __builtin_amdgcn_sched_barrier(0);

#pragma unroll 1
    for (int t = 0; t < 32; t += 2) {
        TILE_BODY(t,     0, c0, c1);
        TILE_BODY(t + 1, 1, c1, c0);
    }
}

extern "C" void kernel_launch(void* const* d_in, const int* in_sizes, int n_in,
                              void* d_out, int out_size, void* d_ws, size_t ws_size,
                              hipStream_t stream)
{
    const float* x   = (const float*)d_in[0];
    const float* h   = (const float*)d_in[1];
    const float* c   = (const float*)d_in[2];
    const float* Wf  = (const float*)d_in[3];
    const float* bf_ = (const float*)d_in[4];
    const float* Wi  = (const float*)d_in[5];
    const float* bi_ = (const float*)d_in[6];
    const float* Wc  = (const float*)d_in[7];
    const float* bc_ = (const float*)d_in[8];
    const float* Wo  = (const float*)d_in[9];
    const float* bo_ = (const float*)d_in[10];
    const float* Wch = (const float*)d_in[11];
    const float* bch = (const float*)d_in[12];

    unsigned short* WgF2 = (unsigned short*)d_ws;         // 512*256 bf16 fragment-linear
    unsigned short* WchF = WgF2 + 512 * 256;              // 128*128 bf16 fragment-linear
    float* out = (float*)d_out;

    int nrows = in_sizes[0] / 128;                        // 262144

    prep_weights<<<dim3(72), dim3(256), 0, stream>>>(Wf, Wi, Wc, Wo, Wch, WgF2, WchF);
    lstm_fused<<<dim3(nrows / 1024), dim3(1024), 0, stream>>>(
        x, h, c, bf_, bi_, bc_, bo_, bch, WgF2, WchF, out, nrows);
}

// Round 20
// 147.350 us; speedup vs baseline: 2.6913x; 2.6913x over previous
//
#include <hip/hip_runtime.h>
#include <hip/hip_bf16.h>

// LSTM block, fused. Inputs fp32, outputs fp32. bf16 MFMA internally.
// r18 structure (weights-in-regs Breg 128/wave + Wreg 16, land-DMA A-path,
// cvt-pass at body top, ONE barrier per 32-row tile) + critical-path trim:
// the o-gate sigmoid and the 8 global c-stores move POST-barrier (they do
// not feed cex); c_new crosses the barrier in 8 regs. Barrier waits
// lgkmcnt(0) vmcnt(0) (publishes A-DMA cross-wave; all in-flight ops are
// >=1/3-body old so the drain is nominal).
// LDS 112K: abuf 2x16K | land 2x32K | cex 2x8K.

typedef __attribute__((ext_vector_type(8))) short bf16x8;   // 8 bf16 = 4 VGPRs
typedef __attribute__((ext_vector_type(4))) float f32x4;

#define AB0   0
#define AB1   16384
#define LAND0 32768
#define LAND1 65536
#define CEX0  98304
#define CEX1  106496

static __device__ __forceinline__ unsigned short f2bf(float f) {
    unsigned int u = __builtin_bit_cast(unsigned int, f);
    u += 0x7FFFu + ((u >> 16) & 1u);      // RNE
    return (unsigned short)(u >> 16);
}

static __device__ __forceinline__ unsigned int cvtpk(float lo, float hi) {
    unsigned int r;
    asm("v_cvt_pk_bf16_f32 %0, %1, %2" : "=v"(r) : "v"(lo), "v"(hi));
    return r;
}

static __device__ __forceinline__ bf16x8 cvt8(f32x4 a, f32x4 b) {
    union { bf16x8 v; unsigned int w[4]; } r;
    r.w[0] = cvtpk(a[0], a[1]);
    r.w[1] = cvtpk(a[2], a[3]);
    r.w[2] = cvtpk(b[0], b[1]);
    r.w[3] = cvtpk(b[2], b[3]);
    return r.v;
}

static __device__ __forceinline__ float fsig(float x) {
    float e = __builtin_amdgcn_exp2f(-1.44269504f * x);
    return __builtin_amdgcn_rcpf(1.0f + e);
}
static __device__ __forceinline__ float ftanh(float x) {
    float e = __builtin_amdgcn_exp2f(2.8853900818f * x);
    return 1.0f - 2.0f * __builtin_amdgcn_rcpf(e + 1.0f);
}

static __device__ __forceinline__ void gload16(const void* gsrc, void* ldst) {
    __builtin_amdgcn_global_load_lds(
        (const __attribute__((address_space(1))) unsigned int*)gsrc,
        (__attribute__((address_space(3))) unsigned int*)ldst,
        16, 0, 0);
}

#define MEMFENCE asm volatile("" ::: "memory")

// ---------------- weight prep: fragment-linear bf16, 16-col gate interleave ----
__global__ void prep_weights(const float* __restrict__ Wf, const float* __restrict__ Wi,
                             const float* __restrict__ Wc, const float* __restrict__ Wo,
                             const float* __restrict__ Wch,
                             unsigned short* __restrict__ WgF,   // 512*256
                             unsigned short* __restrict__ WchF)  // 128*128
{
    int u = blockIdx.x * 256 + threadIdx.x;
    if (u < 16384) {
        int lane = u & 63, g = (u >> 6) & 3, wn = (u >> 8) & 7, ks = u >> 11;
        int l15 = lane & 15, lg = lane >> 4;
        int cg = wn * 16 + l15;
        int k0 = ks * 32 + lg * 8;
        const float* W = (g == 0) ? Wf : (g == 1) ? Wi : (g == 2) ? Wc : Wo;
        union { bf16x8 v; unsigned short s[8]; } r;
#pragma unroll
        for (int i = 0; i < 8; ++i) r.s[i] = f2bf(W[(size_t)(k0 + i) * 128 + cg]);
        *(bf16x8*)(WgF + (size_t)u * 8) = r.v;
    } else if (u < 16384 + 2048) {
        int u2 = u - 16384;
        int lane = u2 & 63, wn = (u2 >> 6) & 7, kt = u2 >> 9;
        int l15 = lane & 15, lg = lane >> 4;
        int col = wn * 16 + l15, k0 = kt * 32 + lg * 8;
        union { bf16x8 v; unsigned short s[8]; } r;
#pragma unroll
        for (int i = 0; i < 8; ++i) r.s[i] = f2bf(Wch[(size_t)(k0 + i) * 128 + col]);
        *(bf16x8*)(WchF + (size_t)u2 * 8) = r.v;
    }
}

// One 32-row tile. CUR = compile-time parity (t & 1).
// CIN = c-input regs for tile T (loaded last body); COUT receives c(T+1).
#define TILE_BODY(T, CUR, CIN, COUT)                                            \
  do {                                                                          \
    const long m0 = base + (long)(T) * 32;                                      \
    /* cvt-pass AT BODY TOP: land[CUR^1] (A(T+1)) -> abuf[CUR^1].               \
       Published by the previous barrier's vmcnt(0). */                         \
    if ((T) < 31) {                                                             \
      const char* ln = lds + ((CUR) ? LAND0 : LAND1) + rowA * 1024;             \
      f32x4 q0 = *(const f32x4*)(ln + (((kgA * 4 + 0) ^ swzA) << 4));           \
      f32x4 q1 = *(const f32x4*)(ln + (((kgA * 4 + 1) ^ swzA) << 4));           \
      f32x4 q2 = *(const f32x4*)(ln + (((kgA * 4 + 2) ^ swzA) << 4));           \
      f32x4 q3 = *(const f32x4*)(ln + (((kgA * 4 + 3) ^ swzA) << 4));           \
      char* fb = lds + ((CUR) ? AB0 : AB1);                                     \
      *(bf16x8*)(fb + aoff0) = cvt8(q0, q1);                                    \
      *(bf16x8*)(fb + aoff1) = cvt8(q2, q3);                                    \
    }                                                                           \
    MEMFENCE;                                                                   \
    /* c-loads(t+1) -> COUT regs (8 scalar loads) */                            \
    if ((T) < 31) {                                                             \
      _Pragma("unroll")                                                         \
      for (int am = 0; am < 2; ++am)                                            \
        _Pragma("unroll")                                                       \
        for (int r = 0; r < 4; ++r)                                             \
          COUT[am * 4 + r] = cg[(m0 + 32 + am * 16 + lg * 4 + r) * 128 + colc]; \
    }                                                                           \
    MEMFENCE;                                                                   \
    /* A-DMA(t+2) -> land[CUR]  (4 ops) */                                      \
    if ((T) < 30) {                                                             \
      char* ad = lds + ((CUR) ? LAND1 : LAND0) + wn * 1024 + lane * 16;         \
      _Pragma("unroll")                                                         \
      for (int j = 0; j < 4; ++j)                                               \
        gload16(dmaA + (m0 + 64 + wn + j * 8) * 128, ad + j * 8192);            \
    }                                                                           \
    MEMFENCE;                                                                   \
    /* GEMM1(t): A bf16 frags from abuf[CUR], B from Breg */                    \
    {                                                                           \
      const char* ab = lds + ((CUR) ? AB1 : AB0);                               \
      _Pragma("unroll")                                                         \
      for (int ks = 0; ks < 8; ++ks) {                                          \
        bf16x8 af0 = *(const bf16x8*)(ab + ks * 1024 + ((lane * 16) ^ (ks << 4)));       \
        bf16x8 af1 = *(const bf16x8*)(ab + (8 + ks) * 1024 + ((lane * 16) ^ (ks << 4))); \
        _Pragma("unroll")                                                       \
        for (int g_ = 0; g_ < 4; ++g_) {                                        \
          acc[0][g_] = __builtin_amdgcn_mfma_f32_16x16x32_bf16(af0, Breg[ks][g_], acc[0][g_], 0, 0, 0); \
          acc[1][g_] = __builtin_amdgcn_mfma_f32_16x16x32_bf16(af1, Breg[ks][g_], acc[1][g_], 0, 0, 0); \
        }                                                                       \
      }                                                                         \
    }                                                                           \
    /* elementwise(t) MINIMAL pre-barrier: f,i,ct -> c_new regs + cex write.    \
       (o-gate sigmoid and global c-store deferred past the barrier.) */        \
    float cn[2][4];                                                             \
    {                                                                           \
      char* cexb = lds + ((CUR) ? CEX1 : CEX0);                                 \
      _Pragma("unroll")                                                         \
      for (int am = 0; am < 2; ++am)                                            \
        _Pragma("unroll")                                                       \
        for (int r = 0; r < 4; ++r) {                                           \
          float f_  = fsig(acc[am][0][r] + bfb);                                \
          float i_  = fsig(acc[am][1][r] + bib);                                \
          float ct_ = ftanh(acc[am][2][r] + bcb);                               \
          float cv_ = f_ * CIN[am * 4 + r] + i_ * ct_;                          \
          cn[am][r] = cv_;                                                      \
          *(unsigned short*)(cexb + (am * 4 + (wn >> 1)) * 1024                 \
               + (cslotbase + lg * 4 + r) * 16 + (l15 & 7) * 2) = f2bf(cv_);    \
        }                                                                       \
    }                                                                           \
    /* ONE barrier: lgkmcnt(0) + vmcnt(0). Publishes cex/abuf (LDS) and        \
       land (A-DMA retired in every wave). All in-flight vm ops are old. */     \
    asm volatile("s_waitcnt lgkmcnt(0) vmcnt(0)" ::: "memory");                 \
    __builtin_amdgcn_sched_barrier(0);                                          \
    __builtin_amdgcn_s_barrier();                                               \
    __builtin_amdgcn_sched_barrier(0);                                          \
    /* post-barrier: c-stores + GEMM2(t) + o-gate + h epilogue (MFMA || VALU    \
       || stores interleave -- none of it gates the next barrier) */            \
    {                                                                           \
      _Pragma("unroll")                                                         \
      for (int am = 0; am < 2; ++am)                                            \
        _Pragma("unroll")                                                       \
        for (int r = 0; r < 4; ++r)                                             \
          coutp[(m0 + am * 16 + lg * 4 + r) * 128 + colc] = cn[am][r];          \
      const char* cexr = lds + ((CUR) ? CEX1 : CEX0);                           \
      f32x4 acc2_0 = {0.f,0.f,0.f,0.f}, acc2_1 = {0.f,0.f,0.f,0.f};             \
      _Pragma("unroll")                                                         \
      for (int kt = 0; kt < 4; ++kt) {                                          \
        bf16x8 p0 = *(const bf16x8*)(cexr + kt * 1024 + lane * 16);             \
        bf16x8 p1 = *(const bf16x8*)(cexr + (4 + kt) * 1024 + lane * 16);       \
        acc2_0 = __builtin_amdgcn_mfma_f32_16x16x32_bf16(p0, Wreg[kt], acc2_0, 0, 0, 0); \
        acc2_1 = __builtin_amdgcn_mfma_f32_16x16x32_bf16(p1, Wreg[kt], acc2_1, 0, 0, 0); \
      }                                                                         \
      _Pragma("unroll")                                                         \
      for (int r = 0; r < 4; ++r) {                                             \
        float o0 = fsig(acc[0][3][r] + bob);                                    \
        houtp[(m0 +      lg * 4 + r) * 128 + colc] = o0 * ftanh(acc2_0[r] + bchb); \
        float o1 = fsig(acc[1][3][r] + bob);                                    \
        houtp[(m0 + 16 + lg * 4 + r) * 128 + colc] = o1 * ftanh(acc2_1[r] + bchb); \
      }                                                                         \
    }                                                                           \
    _Pragma("unroll")                                                           \
    for (int am = 0; am < 2; ++am)                                              \
      _Pragma("unroll")                                                         \
      for (int g_ = 0; g_ < 4; ++g_) acc[am][g_] = (f32x4){0.f,0.f,0.f,0.f};    \
  } while (0)

// ---------------- fused kernel: 1024 rows per 512-thread block, 32-row tiles ----
__global__ __launch_bounds__(512, 2) void lstm_fused(
    const float* __restrict__ xg, const float* __restrict__ hg, const float* __restrict__ cg,
    const float* __restrict__ bfv, const float* __restrict__ biv,
    const float* __restrict__ bcv, const float* __restrict__ bov,
    const float* __restrict__ bchv,
    const unsigned short* __restrict__ WgF, const unsigned short* __restrict__ WchF,
    float* __restrict__ out, int nrows)
{
    __shared__ uint4 lds4[7168];                 // 112 KB
    char* lds = (char*)lds4;

    const int tid  = threadIdx.x;
    const int lane = tid & 63;
    const int wn   = tid >> 6;                   // wave id = col-group = A-row class (mod 8)
    const int l15  = lane & 15;
    const int lg   = lane >> 4;
    const long base = (long)blockIdx.x << 10;    // 1024 rows per block

    float* houtp = out;
    float* coutp = out + (size_t)nrows * 128;

    const int colc = wn * 16 + l15;              // lane-local output column
    const float bfb = bfv[colc], bib = biv[colc], bcb = bcv[colc],
                bob = bov[colc], bchb = bchv[colc];
    const int cslotbase = ((wn & 1) * 2 + (l15 >> 3)) * 16;

    // ---- weights into registers (L2-resident source; read once per block)
    bf16x8 Breg[8][4];                           // [ks][gate] : 128 VGPRs
#pragma unroll
    for (int ks = 0; ks < 8; ++ks)
#pragma unroll
        for (int g = 0; g < 4; ++g)
            Breg[ks][g] = *(const bf16x8*)(WgF + (size_t)((ks * 32 + wn * 4 + g) * 512 + lane * 8));
    bf16x8 Wreg[4];                              // [kt] : 16 VGPRs
#pragma unroll
    for (int kt = 0; kt < 4; ++kt)
        Wreg[kt] = *(const bf16x8*)(WchF + (size_t)((kt * 8 + wn) * 512 + lane * 8));

    // ---- A-DMA source: lane stages 16B unit gu = lane ^ wn of each row
    //      LDS[row][u] = G[row][u ^ (row&7)]; rows wn+8j (row&7 == wn)
    const int gu = lane ^ wn;
    const float* dmaA = ((gu < 32) ? (xg + gu * 4) : (hg + (gu - 32) * 4));

    // ---- cvt-pass thread coords (thread converts 16 k-elems of one row)
    const int rowA = tid >> 4;                   // 0..31
    const int kgA  = tid & 15;                   // 16-elem k-group
    const int swzA = rowA & 7;
    const int ksA  = kgA >> 1;
    const int lgA  = (kgA & 1) * 2;
    const int amA  = rowA >> 4;
    const int l15A = rowA & 15;
    const int aoff0 = (amA * 8 + ksA) * 1024 + ((((lgA    ) * 16 + l15A) * 16) ^ (ksA << 4));
    const int aoff1 = (amA * 8 + ksA) * 1024 + ((((lgA + 1) * 16 + l15A) * 16) ^ (ksA << 4));
    const float* asrc = (kgA < 8) ? (xg + kgA * 16) : (hg + (kgA - 8) * 16);

    // ---- prologue: c(0) -> c0 regs; A(1) DMA -> land1; A(0) direct -> abuf0
    float c0[8], c1[8];
#pragma unroll
    for (int am = 0; am < 2; ++am)
#pragma unroll
        for (int r = 0; r < 4; ++r)
            c0[am * 4 + r] = cg[(base + am * 16 + lg * 4 + r) * 128 + colc];
    MEMFENCE;
    {
        char* ad = lds + LAND1 + wn * 1024 + lane * 16;
#pragma unroll
        for (int j = 0; j < 4; ++j)
            gload16(dmaA + (base + 32 + wn + j * 8) * 128, ad + j * 8192);
    }
    MEMFENCE;
    {
        const float* s = asrc + (base + rowA) * 128;
        f32x4 v0 = ((const f32x4*)s)[0], v1 = ((const f32x4*)s)[1],
              v2 = ((const f32x4*)s)[2], v3 = ((const f32x4*)s)[3];
        *(bf16x8*)(lds + AB0 + aoff0) = cvt8(v0, v1);
        *(bf16x8*)(lds + AB0 + aoff1) = cvt8(v2, v3);
    }
    asm volatile("s_waitcnt lgkmcnt(0) vmcnt(0)" ::: "memory");
    __builtin_amdgcn_sched_barrier(0);
    __builtin_amdgcn_s_barrier();
    __builtin_amdgcn_sched_barrier(0);

    f32x4 acc[2][4];                             // [am][gate]
#pragma unroll
    for (int am = 0; am < 2; ++am)
#pragma unroll
        for (int g = 0; g < 4; ++g) acc[am][g] = {0.f, 0.f, 0.f, 0.f};

#pragma unroll 1
    for (int t = 0; t < 32; t += 2) {
        TILE_BODY(t,     0, c0, c1);
        TILE_BODY(t + 1, 1, c1, c0);
    }
}

extern "C" void kernel_launch(void* const* d_in, const int* in_sizes, int n_in,
                              void* d_out, int out_size, void* d_ws, size_t ws_size,
                              hipStream_t stream)
{
    const float* x   = (const float*)d_in[0];
    const float* h   = (const float*)d_in[1];
    const float* c   = (const float*)d_in[2];
    const float* Wf  = (const float*)d_in[3];
    const float* bf_ = (const float*)d_in[4];
    const float* Wi  = (const float*)d_in[5];
    const float* bi_ = (const float*)d_in[6];
    const float* Wc  = (const float*)d_in[7];
    const float* bc_ = (const float*)d_in[8];
    const float* Wo  = (const float*)d_in[9];
    const float* bo_ = (const float*)d_in[10];
    const float* Wch = (const float*)d_in[11];
    const float* bch = (const float*)d_in[12];

    unsigned short* WgF  = (unsigned short*)d_ws;         // 512*256 bf16 fragment-linear
    unsigned short* WchF = WgF + 512 * 256;               // 128*128 bf16 fragment-linear
    float* out = (float*)d_out;

    int nrows = in_sizes[0] / 128;                        // 262144

    prep_weights<<<dim3(72), dim3(256), 0, stream>>>(Wf, Wi, Wc, Wo, Wch, WgF, WchF);
    lstm_fused<<<dim3(nrows / 1024), dim3(512), 0, stream>>>(
        x, h, c, bf_, bi_, bc_, bo_, bch, WgF, WchF, out, nrows);
}

// Round 21
// 144.086 us; speedup vs baseline: 2.7523x; 1.0227x over previous
//
#include <hip/hip_runtime.h>
#include <hip/hip_bf16.h>

// LSTM block, fused. Inputs fp32, outputs fp32. bf16 MFMA internally.
// FINAL (r18 revert): weights-in-regs (Breg 128 VGPR/wave + Wreg 16,
// gate-interleaved so the 4-gate elementwise is lane-local), A-prefetch via
// global_load_lds DMA into a fp32 landing dbuf (zero register cost, one full
// tile of lead), shared cvt-pass at body top, c-input in ping-pong regs,
// ONE barrier per 32-row tile waiting lgkmcnt(0) vmcnt(8) (retires every
// wave's A-DMA before the barrier publishes it -- cross-wave DMA visibility
// requires the ISSUING wave's vmcnt). sched_barrier(0) around every
// s_barrier. LDS 112K: abuf 2x16K | land 2x32K | cex 2x8K.
// Session ceiling: 8 waves x ~250 regs/wave = 2 waves/SIMD is forced by the
// 256KB register-resident weight panel; 5 schedule variants converge 143+-3us.

typedef __attribute__((ext_vector_type(8))) short bf16x8;   // 8 bf16 = 4 VGPRs
typedef __attribute__((ext_vector_type(4))) float f32x4;

#define AB0   0
#define AB1   16384
#define LAND0 32768
#define LAND1 65536
#define CEX0  98304
#define CEX1  106496

static __device__ __forceinline__ unsigned short f2bf(float f) {
    unsigned int u = __builtin_bit_cast(unsigned int, f);
    u += 0x7FFFu + ((u >> 16) & 1u);      // RNE
    return (unsigned short)(u >> 16);
}

static __device__ __forceinline__ unsigned int cvtpk(float lo, float hi) {
    unsigned int r;
    asm("v_cvt_pk_bf16_f32 %0, %1, %2" : "=v"(r) : "v"(lo), "v"(hi));
    return r;
}

static __device__ __forceinline__ bf16x8 cvt8(f32x4 a, f32x4 b) {
    union { bf16x8 v; unsigned int w[4]; } r;
    r.w[0] = cvtpk(a[0], a[1]);
    r.w[1] = cvtpk(a[2], a[3]);
    r.w[2] = cvtpk(b[0], b[1]);
    r.w[3] = cvtpk(b[2], b[3]);
    return r.v;
}

static __device__ __forceinline__ float fsig(float x) {
    float e = __builtin_amdgcn_exp2f(-1.44269504f * x);
    return __builtin_amdgcn_rcpf(1.0f + e);
}
static __device__ __forceinline__ float ftanh(float x) {
    float e = __builtin_amdgcn_exp2f(2.8853900818f * x);
    return 1.0f - 2.0f * __builtin_amdgcn_rcpf(e + 1.0f);
}

static __device__ __forceinline__ void gload16(const void* gsrc, void* ldst) {
    __builtin_amdgcn_global_load_lds(
        (const __attribute__((address_space(1))) unsigned int*)gsrc,
        (__attribute__((address_space(3))) unsigned int*)ldst,
        16, 0, 0);
}

#define MEMFENCE asm volatile("" ::: "memory")

// ---------------- weight prep: fragment-linear bf16, 16-col gate interleave ----
__global__ void prep_weights(const float* __restrict__ Wf, const float* __restrict__ Wi,
                             const float* __restrict__ Wc, const float* __restrict__ Wo,
                             const float* __restrict__ Wch,
                             unsigned short* __restrict__ WgF,   // 512*256
                             unsigned short* __restrict__ WchF)  // 128*128
{
    int u = blockIdx.x * 256 + threadIdx.x;
    if (u < 16384) {
        int lane = u & 63, g = (u >> 6) & 3, wn = (u >> 8) & 7, ks = u >> 11;
        int l15 = lane & 15, lg = lane >> 4;
        int cg = wn * 16 + l15;
        int k0 = ks * 32 + lg * 8;
        const float* W = (g == 0) ? Wf : (g == 1) ? Wi : (g == 2) ? Wc : Wo;
        union { bf16x8 v; unsigned short s[8]; } r;
#pragma unroll
        for (int i = 0; i < 8; ++i) r.s[i] = f2bf(W[(size_t)(k0 + i) * 128 + cg]);
        *(bf16x8*)(WgF + (size_t)u * 8) = r.v;
    } else if (u < 16384 + 2048) {
        int u2 = u - 16384;
        int lane = u2 & 63, wn = (u2 >> 6) & 7, kt = u2 >> 9;
        int l15 = lane & 15, lg = lane >> 4;
        int col = wn * 16 + l15, k0 = kt * 32 + lg * 8;
        union { bf16x8 v; unsigned short s[8]; } r;
#pragma unroll
        for (int i = 0; i < 8; ++i) r.s[i] = f2bf(Wch[(size_t)(k0 + i) * 128 + col]);
        *(bf16x8*)(WchF + (size_t)u2 * 8) = r.v;
    }
}

// One 32-row tile. CUR = compile-time parity (t & 1).
// CIN = c-input regs for tile T (loaded last body); COUT receives c(T+1).
#define TILE_BODY(T, CUR, CIN, COUT)                                            \
  do {                                                                          \
    const long m0 = base + (long)(T) * 32;                                      \
    /* cvt-pass AT BODY TOP: land[CUR^1] (A(T+1)) -> abuf[CUR^1].               \
       NO guard needed: previous barrier's vmcnt(8) retired every wave's       \
       A(T+1) DMA before publishing. */                                         \
    if ((T) < 31) {                                                             \
      const char* ln = lds + ((CUR) ? LAND0 : LAND1) + rowA * 1024;             \
      f32x4 q0 = *(const f32x4*)(ln + (((kgA * 4 + 0) ^ swzA) << 4));           \
      f32x4 q1 = *(const f32x4*)(ln + (((kgA * 4 + 1) ^ swzA) << 4));           \
      f32x4 q2 = *(const f32x4*)(ln + (((kgA * 4 + 2) ^ swzA) << 4));           \
      f32x4 q3 = *(const f32x4*)(ln + (((kgA * 4 + 3) ^ swzA) << 4));           \
      char* fb = lds + ((CUR) ? AB0 : AB1);                                     \
      *(bf16x8*)(fb + aoff0) = cvt8(q0, q1);                                    \
      *(bf16x8*)(fb + aoff1) = cvt8(q2, q3);                                    \
    }                                                                           \
    MEMFENCE;                                                                   \
    /* c-loads(t+1) -> COUT regs (8 scalar loads) */                            \
    if ((T) < 31) {                                                             \
      _Pragma("unroll")                                                         \
      for (int am = 0; am < 2; ++am)                                            \
        _Pragma("unroll")                                                       \
        for (int r = 0; r < 4; ++r)                                             \
          COUT[am * 4 + r] = cg[(m0 + 32 + am * 16 + lg * 4 + r) * 128 + colc]; \
    }                                                                           \
    MEMFENCE;                                                                   \
    /* A-DMA(t+2) -> land[CUR]  (4 ops) */                                      \
    if ((T) < 30) {                                                             \
      char* ad = lds + ((CUR) ? LAND1 : LAND0) + wn * 1024 + lane * 16;         \
      _Pragma("unroll")                                                         \
      for (int j = 0; j < 4; ++j)                                               \
        gload16(dmaA + (m0 + 64 + wn + j * 8) * 128, ad + j * 8192);            \
    }                                                                           \
    MEMFENCE;                                                                   \
    /* GEMM1(t): A bf16 frags from abuf[CUR], B from Breg */                    \
    {                                                                           \
      const char* ab = lds + ((CUR) ? AB1 : AB0);                               \
      _Pragma("unroll")                                                         \
      for (int ks = 0; ks < 8; ++ks) {                                          \
        bf16x8 af0 = *(const bf16x8*)(ab + ks * 1024 + ((lane * 16) ^ (ks << 4)));       \
        bf16x8 af1 = *(const bf16x8*)(ab + (8 + ks) * 1024 + ((lane * 16) ^ (ks << 4))); \
        _Pragma("unroll")                                                       \
        for (int g_ = 0; g_ < 4; ++g_) {                                        \
          acc[0][g_] = __builtin_amdgcn_mfma_f32_16x16x32_bf16(af0, Breg[ks][g_], acc[0][g_], 0, 0, 0); \
          acc[1][g_] = __builtin_amdgcn_mfma_f32_16x16x32_bf16(af1, Breg[ks][g_], acc[1][g_], 0, 0, 0); \
        }                                                                       \
      }                                                                         \
    }                                                                           \
    /* elementwise(t): c from CIN regs; c_new -> global + c_ex[CUR] */          \
    {                                                                           \
      char* cexb = lds + ((CUR) ? CEX1 : CEX0);                                 \
      _Pragma("unroll")                                                         \
      for (int am = 0; am < 2; ++am)                                            \
        _Pragma("unroll")                                                       \
        for (int r = 0; r < 4; ++r) {                                           \
          float f_  = fsig(acc[am][0][r] + bfb);                                \
          float i_  = fsig(acc[am][1][r] + bib);                                \
          float ct_ = ftanh(acc[am][2][r] + bcb);                               \
          float cv_ = f_ * CIN[am * 4 + r] + i_ * ct_;                          \
          coutp[(m0 + am * 16 + lg * 4 + r) * 128 + colc] = cv_;                \
          *(unsigned short*)(cexb + (am * 4 + (wn >> 1)) * 1024                 \
               + (cslotbase + lg * 4 + r) * 16 + (l15 & 7) * 2) = f2bf(cv_);    \
        }                                                                       \
    }                                                                           \
    /* ONE barrier: lgkmcnt(0) + vmcnt(8). vmcnt(8) leaves only this body's    \
       8 c-stores in flight -- A-DMA (4 ops older) is RETIRED, so the barrier  \
       publishes land[] to all waves. h-stores/c-loads also retired (old). */   \
    asm volatile("s_waitcnt lgkmcnt(0) vmcnt(8)" ::: "memory");                 \
    __builtin_amdgcn_sched_barrier(0);                                          \
    __builtin_amdgcn_s_barrier();                                               \
    __builtin_amdgcn_sched_barrier(0);                                          \
    /* GEMM2(t) (c_ex[CUR] x Wreg) + h epilogue */                              \
    {                                                                           \
      const char* cexr = lds + ((CUR) ? CEX1 : CEX0);                           \
      f32x4 acc2_0 = {0.f,0.f,0.f,0.f}, acc2_1 = {0.f,0.f,0.f,0.f};             \
      _Pragma("unroll")                                                         \
      for (int kt = 0; kt < 4; ++kt) {                                          \
        bf16x8 p0 = *(const bf16x8*)(cexr + kt * 1024 + lane * 16);             \
        bf16x8 p1 = *(const bf16x8*)(cexr + (4 + kt) * 1024 + lane * 16);       \
        acc2_0 = __builtin_amdgcn_mfma_f32_16x16x32_bf16(p0, Wreg[kt], acc2_0, 0, 0, 0); \
        acc2_1 = __builtin_amdgcn_mfma_f32_16x16x32_bf16(p1, Wreg[kt], acc2_1, 0, 0, 0); \
      }                                                                         \
      _Pragma("unroll")                                                         \
      for (int r = 0; r < 4; ++r) {                                             \
        float o0 = fsig(acc[0][3][r] + bob);                                    \
        houtp[(m0 +      lg * 4 + r) * 128 + colc] = o0 * ftanh(acc2_0[r] + bchb); \
        float o1 = fsig(acc[1][3][r] + bob);                                    \
        houtp[(m0 + 16 + lg * 4 + r) * 128 + colc] = o1 * ftanh(acc2_1[r] + bchb); \
      }                                                                         \
    }                                                                           \
    _Pragma("unroll")                                                           \
    for (int am = 0; am < 2; ++am)                                              \
      _Pragma("unroll")                                                         \
      for (int g_ = 0; g_ < 4; ++g_) acc[am][g_] = (f32x4){0.f,0.f,0.f,0.f};    \
  } while (0)

// ---------------- fused kernel: 1024 rows per 512-thread block, 32-row tiles ----
__global__ __launch_bounds__(512, 2) void lstm_fused(
    const float* __restrict__ xg, const float* __restrict__ hg, const float* __restrict__ cg,
    const float* __restrict__ bfv, const float* __restrict__ biv,
    const float* __restrict__ bcv, const float* __restrict__ bov,
    const float* __restrict__ bchv,
    const unsigned short* __restrict__ WgF, const unsigned short* __restrict__ WchF,
    float* __restrict__ out, int nrows)
{
    __shared__ uint4 lds4[7168];                 // 112 KB
    char* lds = (char*)lds4;

    const int tid  = threadIdx.x;
    const int lane = tid & 63;
    const int wn   = tid >> 6;                   // wave id = col-group = A-row class (mod 8)
    const int l15  = lane & 15;
    const int lg   = lane >> 4;
    const long base = (long)blockIdx.x << 10;    // 1024 rows per block

    float* houtp = out;
    float* coutp = out + (size_t)nrows * 128;

    const int colc = wn * 16 + l15;              // lane-local output column
    const float bfb = bfv[colc], bib = biv[colc], bcb = bcv[colc],
                bob = bov[colc], bchb = bchv[colc];
    const int cslotbase = ((wn & 1) * 2 + (l15 >> 3)) * 16;

    // ---- weights into registers (L2-resident source; read once per block)
    bf16x8 Breg[8][4];                           // [ks][gate] : 128 VGPRs
#pragma unroll
    for (int ks = 0; ks < 8; ++ks)
#pragma unroll
        for (int g = 0; g < 4; ++g)
            Breg[ks][g] = *(const bf16x8*)(WgF + (size_t)((ks * 32 + wn * 4 + g) * 512 + lane * 8));
    bf16x8 Wreg[4];                              // [kt] : 16 VGPRs
#pragma unroll
    for (int kt = 0; kt < 4; ++kt)
        Wreg[kt] = *(const bf16x8*)(WchF + (size_t)((kt * 8 + wn) * 512 + lane * 8));

    // ---- A-DMA source: lane stages 16B unit gu = lane ^ wn of each row
    //      LDS[row][u] = G[row][u ^ (row&7)]; rows wn+8j (row&7 == wn)
    const int gu = lane ^ wn;
    const float* dmaA = ((gu < 32) ? (xg + gu * 4) : (hg + (gu - 32) * 4));

    // ---- cvt-pass thread coords (thread converts 16 k-elems of one row)
    const int rowA = tid >> 4;                   // 0..31
    const int kgA  = tid & 15;                   // 16-elem k-group
    const int swzA = rowA & 7;
    const int ksA  = kgA >> 1;
    const int lgA  = (kgA & 1) * 2;
    const int amA  = rowA >> 4;
    const int l15A = rowA & 15;
    const int aoff0 = (amA * 8 + ksA) * 1024 + ((((lgA    ) * 16 + l15A) * 16) ^ (ksA << 4));
    const int aoff1 = (amA * 8 + ksA) * 1024 + ((((lgA + 1) * 16 + l15A) * 16) ^ (ksA << 4));
    const float* asrc = (kgA < 8) ? (xg + kgA * 16) : (hg + (kgA - 8) * 16);

    // ---- prologue: c(0) -> c0 regs; A(1) DMA -> land1; A(0) direct -> abuf0
    float c0[8], c1[8];
#pragma unroll
    for (int am = 0; am < 2; ++am)
#pragma unroll
        for (int r = 0; r < 4; ++r)
            c0[am * 4 + r] = cg[(base + am * 16 + lg * 4 + r) * 128 + colc];
    MEMFENCE;
    {
        char* ad = lds + LAND1 + wn * 1024 + lane * 16;
#pragma unroll
        for (int j = 0; j < 4; ++j)
            gload16(dmaA + (base + 32 + wn + j * 8) * 128, ad + j * 8192);
    }
    MEMFENCE;
    {
        const float* s = asrc + (base + rowA) * 128;
        f32x4 v0 = ((const f32x4*)s)[0], v1 = ((const f32x4*)s)[1],
              v2 = ((const f32x4*)s)[2], v3 = ((const f32x4*)s)[3];
        *(bf16x8*)(lds + AB0 + aoff0) = cvt8(v0, v1);
        *(bf16x8*)(lds + AB0 + aoff1) = cvt8(v2, v3);
    }
    asm volatile("s_waitcnt lgkmcnt(0) vmcnt(0)" ::: "memory");
    __builtin_amdgcn_sched_barrier(0);
    __builtin_amdgcn_s_barrier();
    __builtin_amdgcn_sched_barrier(0);

    f32x4 acc[2][4];                             // [am][gate]
#pragma unroll
    for (int am = 0; am < 2; ++am)
#pragma unroll
        for (int g = 0; g < 4; ++g) acc[am][g] = {0.f, 0.f, 0.f, 0.f};

#pragma unroll 1
    for (int t = 0; t < 32; t += 2) {
        TILE_BODY(t,     0, c0, c1);
        TILE_BODY(t + 1, 1, c1, c0);
    }
}

extern "C" void kernel_launch(void* const* d_in, const int* in_sizes, int n_in,
                              void* d_out, int out_size, void* d_ws, size_t ws_size,
                              hipStream_t stream)
{
    const float* x   = (const float*)d_in[0];
    const float* h   = (const float*)d_in[1];
    const float* c   = (const float*)d_in[2];
    const float* Wf  = (const float*)d_in[3];
    const float* bf_ = (const float*)d_in[4];
    const float* Wi  = (const float*)d_in[5];
    const float* bi_ = (const float*)d_in[6];
    const float* Wc  = (const float*)d_in[7];
    const float* bc_ = (const float*)d_in[8];
    const float* Wo  = (const float*)d_in[9];
    const float* bo_ = (const float*)d_in[10];
    const float* Wch = (const float*)d_in[11];
    const float* bch = (const float*)d_in[12];

    unsigned short* WgF  = (unsigned short*)d_ws;         // 512*256 bf16 fragment-linear
    unsigned short* WchF = WgF + 512 * 256;               // 128*128 bf16 fragment-linear
    float* out = (float*)d_out;

    int nrows = in_sizes[0] / 128;                        // 262144

    prep_weights<<<dim3(72), dim3(256), 0, stream>>>(Wf, Wi, Wc, Wo, Wch, WgF, WchF);
    lstm_fused<<<dim3(nrows / 1024), dim3(512), 0, stream>>>(
        x, h, c, bf_, bi_, bc_, bo_, bch, WgF, WchF, out, nrows);
}